// Round 10
// baseline (469.756 us; speedup 1.0000x reference)
//
#include <hip/hip_runtime.h>

#define CG   16
#define HWN  4096
#define PSTRIDE 2560   // floats per group: sh 1024 | sw 1024 | W5 448 | A1 16 | ca 16 | Ct 1

// Static device param buffer (5.24 MB) — graph-capture safe.
__device__ float g_params[512 * PSTRIDE];

__device__ __forceinline__ float sigm(float x) { return 1.0f / (1.0f + __expf(-x)); }

// ============================ Kernel P: per-group prep ============================
// (unchanged — verified)
__global__ __launch_bounds__(512, 4) void ema_prep(
    const float* __restrict__ x,
    const float* __restrict__ w1, const float* __restrict__ b1,
    const float* __restrict__ w3, const float* __restrict__ b3,
    const float* __restrict__ w5, const float* __restrict__ b5,
    const float* __restrict__ gnw, const float* __restrict__ gnb,
    const float* __restrict__ ew, const float* __restrict__ eb)
{
  __shared__ float s_row[16][64], s_col[16][64];
  __shared__ float s_RS[16][25];
  __shared__ float s_p2[16][16], s_p3[16][16];
  __shared__ __align__(16) float s_sh[16][64];
  __shared__ __align__(16) float s_sw[16][64];
  __shared__ __align__(16) float s_W5[16][28];
  __shared__ float s_w1[256], s_b1[16], s_gnw[16], s_gnb[16], s_b3[16], s_b5[16], s_ecaw[3], s_ecab[1];
  __shared__ float s_m2[16], s_m3[16], s_sm1[16], s_sm2[16], s_sm3[16];
  __shared__ float s_a1[16], s_a2[16], s_a3[16], s_total[16], s_ca[16];
  __shared__ float s_A1[16], s_Cc[16];
  __shared__ float s_scal[2];     // [0]=total constant Ct, [1]=bias_eff

  const int g = blockIdx.x;
  const int t = threadIdx.x;
  const int wv = t >> 6;
  const int ln = t & 63;
  const float* px = x + (size_t)g * CG * HWN;

  // ---------------- Phase 1: row/col sums; wave w owns channels 2w, 2w+1 ----------------
  {
    const int j4 = ln & 15;
    const int rr = ln >> 4;
    #pragma unroll 1
    for (int cc = 0; cc < 2; ++cc) {
      const int c = 2 * wv + cc;
      float rs[16];
      float cp0 = 0.f, cp1 = 0.f, cp2 = 0.f, cp3 = 0.f;
      #pragma unroll
      for (int j = 0; j < 16; ++j) {
        float4 v = *(const float4*)(px + c * HWN + (rr + 4 * j) * 64 + 4 * j4);
        rs[j] = v.x + v.y + v.z + v.w;
        cp0 += v.x; cp1 += v.y; cp2 += v.z; cp3 += v.w;
      }
      #pragma unroll
      for (int j = 0; j < 16; ++j) {
        float r = rs[j];
        r += __shfl_xor(r, 1); r += __shfl_xor(r, 2);
        r += __shfl_xor(r, 4); r += __shfl_xor(r, 8);
        if (j4 == 0) s_row[c][rr + 4 * j] = r;
      }
      cp0 += __shfl_xor(cp0, 16); cp0 += __shfl_xor(cp0, 32);
      cp1 += __shfl_xor(cp1, 16); cp1 += __shfl_xor(cp1, 32);
      cp2 += __shfl_xor(cp2, 16); cp2 += __shfl_xor(cp2, 32);
      cp3 += __shfl_xor(cp3, 16); cp3 += __shfl_xor(cp3, 32);
      if (rr == 0) *(float4*)&s_col[c][4 * j4] = make_float4(cp0, cp1, cp2, cp3);
    }
  }
  if (t < 256) s_w1[t] = w1[t];
  if (t < 16) {
    s_b1[t]  = b1[t];  s_gnw[t] = gnw[t]; s_gnb[t] = gnb[t];
    s_b3[t]  = b3[t];  s_b5[t]  = b5[t];
  }
  if (t < 3)  s_ecaw[t] = ew[t];
  if (t == 0) s_ecab[0] = eb[0];
  __syncthreads();

  if (t < 16) { float s = 0.f; for (int y = 0; y < 64; ++y) s += s_row[t][y]; s_total[t] = s; }
  __syncthreads();

  // ---------------- conv1x1 (+sigmoid), 5x5 region sums ----------------
  #pragma unroll
  for (int m = 0; m < 4; ++m) {
    int idx = t + 512 * m; int o = idx >> 7, pos = idx & 127;
    float acc = s_b1[o];
    const float inv64 = 1.0f / 64.0f;
    #pragma unroll
    for (int i = 0; i < 16; ++i) {
      float v = (pos < 64 ? s_row[i][pos] : s_col[i][pos - 64]) * inv64;
      acc += s_w1[o * 16 + i] * v;
    }
    float sg = sigm(acc);
    if (pos < 64) s_sh[o][pos] = sg; else s_sw[o][pos - 64] = sg;
  }
  if (t < 400) {
    int i = t / 25, kk = t % 25;
    int dy = kk / 5 - 2, dx = kk % 5 - 2;
    int a  = dy > 0 ? dy : 0,   b  = 64 + (dy < 0 ? dy : 0);
    int cl = dx > 0 ? dx : 0,   d  = 64 + (dx < 0 ? dx : 0);
    float S = s_total[i];
    if (a > 0)  S -= s_row[i][0];
    if (a > 1)  S -= s_row[i][1];
    if (b < 64) S -= s_row[i][63];
    if (b < 63) S -= s_row[i][62];
    for (int x0 = 0; x0 < cl; ++x0) {
      float cv = s_col[i][x0];
      if (a > 0)  cv -= px[i * HWN + 0 * 64  + x0];
      if (a > 1)  cv -= px[i * HWN + 1 * 64  + x0];
      if (b < 64) cv -= px[i * HWN + 63 * 64 + x0];
      if (b < 63) cv -= px[i * HWN + 62 * 64 + x0];
      S -= cv;
    }
    for (int x0 = d; x0 < 64; ++x0) {
      float cv = s_col[i][x0];
      if (a > 0)  cv -= px[i * HWN + 0 * 64  + x0];
      if (a > 1)  cv -= px[i * HWN + 1 * 64  + x0];
      if (b < 64) cv -= px[i * HWN + 63 * 64 + x0];
      if (b < 63) cv -= px[i * HWN + 62 * 64 + x0];
      S -= cv;
    }
    s_RS[i][kk] = S;
  }
  __syncthreads();

  // ---------------- mean(x2), mean(x3) ----------------
  if (t < 256) {
    int o = t >> 4, i = t & 15;
    float p2 = 0.f, p3 = 0.f;
    const float* w3b = w3 + (o * 16 + i) * 9;
    const float* w5b = w5 + (o * 16 + i) * 25;
    #pragma unroll
    for (int ky = 0; ky < 3; ++ky)
      #pragma unroll
      for (int kx = 0; kx < 3; ++kx)
        p2 += w3b[ky * 3 + kx] * s_RS[i][(ky + 1) * 5 + (kx + 1)];
    #pragma unroll
    for (int kk = 0; kk < 25; ++kk) p3 += w5b[kk] * s_RS[i][kk];
    s_p2[o][i] = p2; s_p3[o][i] = p3;
  }
  __syncthreads();
  if (t < 16)      { float s = 0.f; for (int i = 0; i < 16; ++i) s += s_p2[t][i];      s_m2[t] = s_b3[t] + s * (1.0f/4096.0f); }
  else if (t < 32) { int o = t - 16; float s = 0.f; for (int i = 0; i < 16; ++i) s += s_p3[o][i]; s_m3[o] = s_b5[o] + s * (1.0f/4096.0f); }
  __syncthreads();

  // ---------------- softmaxes (mean(x1) == gn_b exactly) ----------------
  if (t < 3) {
    const float* m = (t == 0) ? s_gnb : (t == 1) ? s_m2 : s_m3;
    float* dst     = (t == 0) ? s_sm1 : (t == 1) ? s_sm2 : s_sm3;
    float mx = m[0];
    for (int c = 1; c < 16; ++c) mx = fmaxf(mx, m[c]);
    float e[16], ssum = 0.f;
    for (int c = 0; c < 16; ++c) { e[c] = __expf(m[c] - mx); ssum += e[c]; }
    float r = 1.0f / ssum;
    for (int c = 0; c < 16; ++c) dst[c] = e[c] * r;
  }
  __syncthreads();

  // ---------------- ECA (ca) and mixing coefficients ----------------
  if (t < 16) {
    int c = t;
    float casum = 0.f;
    #pragma unroll
    for (int v = 0; v < 3; ++v) {
      const float* m = (v == 0) ? s_gnb : (v == 1) ? s_m2 : s_m3;
      float acc = s_ecab[0] + s_ecaw[1] * m[c];
      if (c > 0)  acc += s_ecaw[0] * m[c - 1];
      if (c < 15) acc += s_ecaw[2] * m[c + 1];
      casum += sigm(acc);
    }
    s_ca[c] = casum;
    s_a1[c] = s_sm2[c] + s_sm3[c];
    s_a2[c] = s_sm1[c] + s_sm3[c];
    s_a3[c] = s_sm1[c] + s_sm2[c];
  }
  __syncthreads();

  // ---------------- effective 5x5 kernel + bias_eff ----------------
  if (t == 0) {
    float s = 0.f;
    for (int o = 0; o < 16; ++o) s += s_a2[o] * s_b3[o] + s_a3[o] * s_b5[o];
    s_scal[1] = s;
  }
  if (t < 448) {
    if (t < 400) {
      int i = t / 25, kk = t % 25, ky = kk / 5, kx = kk % 5;
      float acc = 0.f;
      #pragma unroll
      for (int o = 0; o < 16; ++o) acc += s_a3[o] * w5[((o * 16 + i) * 5 + ky) * 5 + kx];
      if (ky >= 1 && ky <= 3 && kx >= 1 && kx <= 3) {
        #pragma unroll
        for (int o = 0; o < 16; ++o) acc += s_a2[o] * w3[((o * 16 + i) * 3 + (ky - 1)) * 3 + (kx - 1)];
      }
      s_W5[i][kk] = acc;
    } else {
      int q = t - 400; s_W5[q / 3][25 + q % 3] = 0.f;
    }
  }

  // ---------------- gated GN stats: gs = sum(x*sh*sw), gq = sum((.)^2) ----------------
  {
    const int j4 = ln & 15;
    const int rr = ln >> 4;
    #pragma unroll 1
    for (int cc = 0; cc < 2; ++cc) {
      const int c = 2 * wv + cc;
      float gs = 0.f, gq = 0.f;
      const float4 swq = *(const float4*)&s_sw[c][4 * j4];
      #pragma unroll
      for (int j = 0; j < 16; ++j) {
        const int y = rr + 4 * j;
        float4 v = *(const float4*)(px + c * HWN + y * 64 + 4 * j4);
        const float shv = s_sh[c][y];
        float g0 = v.x * shv * swq.x, g1 = v.y * shv * swq.y;
        float g2 = v.z * shv * swq.z, g3 = v.w * shv * swq.w;
        gs += (g0 + g1) + (g2 + g3);
        gq += (g0 * g0 + g1 * g1) + (g2 * g2 + g3 * g3);
      }
      gs += __shfl_xor(gs, 1);  gq += __shfl_xor(gq, 1);
      gs += __shfl_xor(gs, 2);  gq += __shfl_xor(gq, 2);
      gs += __shfl_xor(gs, 4);  gq += __shfl_xor(gq, 4);
      gs += __shfl_xor(gs, 8);  gq += __shfl_xor(gq, 8);
      gs += __shfl_xor(gs, 16); gq += __shfl_xor(gq, 16);
      gs += __shfl_xor(gs, 32); gq += __shfl_xor(gq, 32);
      if (ln == 0) {
        float mu  = gs * (1.0f / 4096.0f);
        float var = gq * (1.0f / 4096.0f) - mu * mu;
        float inv = rsqrtf(var + 1e-5f);
        s_A1[c] = s_a1[c] * s_gnw[c] * inv;
        s_Cc[c] = s_a1[c] * (s_gnb[c] - mu * s_gnw[c] * inv);
      }
    }
  }
  __syncthreads();
  if (t == 0) {
    float s = s_scal[1];
    for (int c = 0; c < 16; ++c) s += s_Cc[c];
    s_scal[0] = s;
  }
  __syncthreads();

  // ---------------- write params ----------------
  float* wp = g_params + (size_t)g * PSTRIDE;
  for (int i = t; i < 1024; i += 512) wp[i]        = s_sh[i >> 6][i & 63];
  for (int i = t; i < 1024; i += 512) wp[1024 + i] = s_sw[i >> 6][i & 63];
  if (t < 448) wp[2048 + t] = s_W5[t / 28][t % 28];
  if (t < 16) { wp[2496 + t] = s_A1[t]; wp[2512 + t] = s_ca[t]; }
  if (t == 0) wp[2528] = s_scal[0];
}

// ============================ Kernel M: register-window conv + output ============================
// lane = column; wave owns an 8-row band; ws[8] accumulators + Wk[25] weights in regs.
// ROUND 10: (a) BRANCH-FREE row loads — clamp the address, zero the VALUE for the
// <=2 edge rows via wave-uniform selects. Round 9's per-row `if (a in range)`
// fenced each load in its own branch block: 12 serial latency exposures per
// channel instead of 1 (VGPR=52 proved the Wk hoist landed; dur only -12us ->
// loads, not the DS pipe, are the limiter). (b) T14 channel pipeline: load
// channel c+1 rows into vn[12] before computing on vc[12]; the vmcnt wait lands
// after ~650 cy of shuffle+FMA. All array indices compile-time (rule #20).
__global__ __launch_bounds__(256, 4) void ema_main(
    const float* __restrict__ x, float* __restrict__ out)
{
  __shared__ float m_sh[16][64];
  __shared__ float m_sw[16][64];
  __shared__ float m_W5[16][28];
  __shared__ float m_A1[16], m_ca[16];
  __shared__ float m_Ct[1];

  const int bid  = blockIdx.x;
  const int g    = bid >> 1;          // group
  const int half = bid & 1;           // rows 0..31 / 32..63
  const int t    = threadIdx.x;
  const int wv   = t >> 6;            // wave 0..3
  const int ln   = t & 63;            // lane = column
  const int r0   = (half * 4 + wv) * 8;   // band start row

  const float* px   = x   + (size_t)g * CG * HWN;
  float*       pout = out + (size_t)g * CG * HWN;
  const float* wp   = g_params + (size_t)g * PSTRIDE;

  for (int i = t; i < 1024; i += 256) m_sh[i >> 6][i & 63] = wp[i];
  for (int i = t; i < 1024; i += 256) m_sw[i >> 6][i & 63] = wp[1024 + i];
  for (int i = t; i < 448; i += 256)  m_W5[i / 28][i % 28] = wp[2048 + i];
  if (t < 16) { m_A1[t] = wp[2496 + t]; m_ca[t] = wp[2512 + t]; }
  if (t == 0) m_Ct[0] = wp[2528];
  __syncthreads();   // the only barrier

  // clamped row offsets (wave-uniform, hoisted): input row for slot i is r0-2+i
  int rofs[12];
  #pragma unroll
  for (int i = 0; i < 12; ++i) {
    int a = r0 - 2 + i;
    int ac = a < 0 ? 0 : (a > 63 ? 63 : a);
    rofs[i] = ac * 64 + ln;
  }
  const bool loEdge = (r0 == 0);    // slots 0,1 invalid
  const bool hiEdge = (r0 == 56);   // slots 10,11 invalid

  float ws[8];
  #pragma unroll
  for (int j = 0; j < 8; ++j) ws[j] = 0.f;

  // prologue: channel 0 rows (branch-free loads, then value-mask edges)
  float vc[12];
  #pragma unroll
  for (int i = 0; i < 12; ++i) vc[i] = px[rofs[i]];
  if (loEdge) { vc[0] = 0.f; vc[1] = 0.f; }
  if (hiEdge) { vc[10] = 0.f; vc[11] = 0.f; }

  #pragma unroll 1
  for (int c = 0; c < 16; ++c) {
    // ---- issue next channel's 12 loads first (latency hides under compute) ----
    float vn[12];
    if (c < 15) {
      const float* pn = px + (c + 1) * HWN;
      #pragma unroll
      for (int i = 0; i < 12; ++i) vn[i] = pn[rofs[i]];
    }
    // ---- compute channel c from vc (registers only + shuffles) ----
    const float swc = m_sw[c][ln];
    const float A1c = m_A1[c];
    float Wk[25];
    #pragma unroll
    for (int m = 0; m < 25; ++m) Wk[m] = m_W5[c][m];
    #pragma unroll
    for (int i = 0; i < 12; ++i) {
      const float v = vc[i];
      float l1 = __shfl_up(v, 1);   l1 = (ln >= 1)  ? l1 : 0.f;
      float l2 = __shfl_up(v, 2);   l2 = (ln >= 2)  ? l2 : 0.f;
      float r1 = __shfl_down(v, 1); r1 = (ln <= 62) ? r1 : 0.f;
      float r2 = __shfl_down(v, 2); r2 = (ln <= 61) ? r2 : 0.f;
      const int jlo = (i - 4 < 0) ? 0 : i - 4;      // const after unroll
      const int jhi = (i > 7) ? 7 : i;
      #pragma unroll
      for (int j = jlo; j <= jhi; ++j) {
        const int k = i - j;                        // tap row 0..4, const
        ws[j] += Wk[5 * k + 0] * l2 + Wk[5 * k + 1] * l1 + Wk[5 * k + 2] * v
               + Wk[5 * k + 3] * r1 + Wk[5 * k + 4] * r2;
      }
      if (i >= 2 && i <= 9) {                       // gated GN term (center row)
        ws[i - 2] += (A1c * m_sh[c][r0 + i - 2]) * (swc * v);
      }
    }
    // ---- commit staged rows (vmcnt wait lands HERE, after compute) ----
    if (c < 15) {
      #pragma unroll
      for (int i = 0; i < 12; ++i) vc[i] = vn[i];
      if (loEdge) { vc[0] = 0.f; vc[1] = 0.f; }
      if (hiEdge) { vc[10] = 0.f; vc[11] = 0.f; }
    }
  }

  // epilogue: out = x * ca[c] * sigm(ws + Ct)
  const float Ct = m_Ct[0];
  float f[8];
  #pragma unroll
  for (int j = 0; j < 8; ++j) f[j] = sigm(ws[j] + Ct);

  #pragma unroll 1
  for (int c = 0; c < 16; ++c) {
    const float cav = m_ca[c];
    const float* xp = px   + c * HWN + r0 * 64 + ln;
    float*       op = pout + c * HWN + r0 * 64 + ln;
    #pragma unroll
    for (int j = 0; j < 8; ++j) {
      op[j * 64] = xp[j * 64] * (cav * f[j]);
    }
  }
}

extern "C" void kernel_launch(void* const* d_in, const int* in_sizes, int n_in,
                              void* d_out, int out_size, void* d_ws, size_t ws_size,
                              hipStream_t stream) {
  const float* X  = (const float*)d_in[0];
  const float* W1 = (const float*)d_in[1];
  const float* B1 = (const float*)d_in[2];
  const float* W3 = (const float*)d_in[3];
  const float* B3 = (const float*)d_in[4];
  const float* W5 = (const float*)d_in[5];
  const float* B5 = (const float*)d_in[6];
  const float* GW = (const float*)d_in[7];
  const float* GB = (const float*)d_in[8];
  const float* EW = (const float*)d_in[9];
  const float* EB = (const float*)d_in[10];
  float* O = (float*)d_out;
  ema_prep<<<dim3(512), dim3(512), 0, stream>>>(X, W1, B1, W3, B3, W5, B5, GW, GB, EW, EB);
  ema_main<<<dim3(1024), dim3(256), 0, stream>>>(X, O);
}

// Round 12
// 338.064 us; speedup vs baseline: 1.3895x; 1.3895x over previous
//
#include <hip/hip_runtime.h>

#define CG   16
#define HWN  4096
#define PSTRIDE 2560   // floats per group: sh 1024 | sw 1024 | W5 448 | A1 16 | ca 16 | Ct 1

// Static device param buffer (5.24 MB) — graph-capture safe.
__device__ float g_params[512 * PSTRIDE];

__device__ __forceinline__ float sigm(float x) { return 1.0f / (1.0f + __expf(-x)); }

// ============================ Kernel P: per-group prep ============================
// (unchanged — verified)
__global__ __launch_bounds__(512, 4) void ema_prep(
    const float* __restrict__ x,
    const float* __restrict__ w1, const float* __restrict__ b1,
    const float* __restrict__ w3, const float* __restrict__ b3,
    const float* __restrict__ w5, const float* __restrict__ b5,
    const float* __restrict__ gnw, const float* __restrict__ gnb,
    const float* __restrict__ ew, const float* __restrict__ eb)
{
  __shared__ float s_row[16][64], s_col[16][64];
  __shared__ float s_RS[16][25];
  __shared__ float s_p2[16][16], s_p3[16][16];
  __shared__ __align__(16) float s_sh[16][64];
  __shared__ __align__(16) float s_sw[16][64];
  __shared__ __align__(16) float s_W5[16][28];
  __shared__ float s_w1[256], s_b1[16], s_gnw[16], s_gnb[16], s_b3[16], s_b5[16], s_ecaw[3], s_ecab[1];
  __shared__ float s_m2[16], s_m3[16], s_sm1[16], s_sm2[16], s_sm3[16];
  __shared__ float s_a1[16], s_a2[16], s_a3[16], s_total[16], s_ca[16];
  __shared__ float s_A1[16], s_Cc[16];
  __shared__ float s_scal[2];     // [0]=total constant Ct, [1]=bias_eff

  const int g = blockIdx.x;
  const int t = threadIdx.x;
  const int wv = t >> 6;
  const int ln = t & 63;
  const float* px = x + (size_t)g * CG * HWN;

  // ---------------- Phase 1: row/col sums; wave w owns channels 2w, 2w+1 ----------------
  {
    const int j4 = ln & 15;
    const int rr = ln >> 4;
    #pragma unroll 1
    for (int cc = 0; cc < 2; ++cc) {
      const int c = 2 * wv + cc;
      float rs[16];
      float cp0 = 0.f, cp1 = 0.f, cp2 = 0.f, cp3 = 0.f;
      #pragma unroll
      for (int j = 0; j < 16; ++j) {
        float4 v = *(const float4*)(px + c * HWN + (rr + 4 * j) * 64 + 4 * j4);
        rs[j] = v.x + v.y + v.z + v.w;
        cp0 += v.x; cp1 += v.y; cp2 += v.z; cp3 += v.w;
      }
      #pragma unroll
      for (int j = 0; j < 16; ++j) {
        float r = rs[j];
        r += __shfl_xor(r, 1); r += __shfl_xor(r, 2);
        r += __shfl_xor(r, 4); r += __shfl_xor(r, 8);
        if (j4 == 0) s_row[c][rr + 4 * j] = r;
      }
      cp0 += __shfl_xor(cp0, 16); cp0 += __shfl_xor(cp0, 32);
      cp1 += __shfl_xor(cp1, 16); cp1 += __shfl_xor(cp1, 32);
      cp2 += __shfl_xor(cp2, 16); cp2 += __shfl_xor(cp2, 32);
      cp3 += __shfl_xor(cp3, 16); cp3 += __shfl_xor(cp3, 32);
      if (rr == 0) *(float4*)&s_col[c][4 * j4] = make_float4(cp0, cp1, cp2, cp3);
    }
  }
  if (t < 256) s_w1[t] = w1[t];
  if (t < 16) {
    s_b1[t]  = b1[t];  s_gnw[t] = gnw[t]; s_gnb[t] = gnb[t];
    s_b3[t]  = b3[t];  s_b5[t]  = b5[t];
  }
  if (t < 3)  s_ecaw[t] = ew[t];
  if (t == 0) s_ecab[0] = eb[0];
  __syncthreads();

  if (t < 16) { float s = 0.f; for (int y = 0; y < 64; ++y) s += s_row[t][y]; s_total[t] = s; }
  __syncthreads();

  // ---------------- conv1x1 (+sigmoid), 5x5 region sums ----------------
  #pragma unroll
  for (int m = 0; m < 4; ++m) {
    int idx = t + 512 * m; int o = idx >> 7, pos = idx & 127;
    float acc = s_b1[o];
    const float inv64 = 1.0f / 64.0f;
    #pragma unroll
    for (int i = 0; i < 16; ++i) {
      float v = (pos < 64 ? s_row[i][pos] : s_col[i][pos - 64]) * inv64;
      acc += s_w1[o * 16 + i] * v;
    }
    float sg = sigm(acc);
    if (pos < 64) s_sh[o][pos] = sg; else s_sw[o][pos - 64] = sg;
  }
  if (t < 400) {
    int i = t / 25, kk = t % 25;
    int dy = kk / 5 - 2, dx = kk % 5 - 2;
    int a  = dy > 0 ? dy : 0,   b  = 64 + (dy < 0 ? dy : 0);
    int cl = dx > 0 ? dx : 0,   d  = 64 + (dx < 0 ? dx : 0);
    float S = s_total[i];
    if (a > 0)  S -= s_row[i][0];
    if (a > 1)  S -= s_row[i][1];
    if (b < 64) S -= s_row[i][63];
    if (b < 63) S -= s_row[i][62];
    for (int x0 = 0; x0 < cl; ++x0) {
      float cv = s_col[i][x0];
      if (a > 0)  cv -= px[i * HWN + 0 * 64  + x0];
      if (a > 1)  cv -= px[i * HWN + 1 * 64  + x0];
      if (b < 64) cv -= px[i * HWN + 63 * 64 + x0];
      if (b < 63) cv -= px[i * HWN + 62 * 64 + x0];
      S -= cv;
    }
    for (int x0 = d; x0 < 64; ++x0) {
      float cv = s_col[i][x0];
      if (a > 0)  cv -= px[i * HWN + 0 * 64  + x0];
      if (a > 1)  cv -= px[i * HWN + 1 * 64  + x0];
      if (b < 64) cv -= px[i * HWN + 63 * 64 + x0];
      if (b < 63) cv -= px[i * HWN + 62 * 64 + x0];
      S -= cv;
    }
    s_RS[i][kk] = S;
  }
  __syncthreads();

  // ---------------- mean(x2), mean(x3) ----------------
  if (t < 256) {
    int o = t >> 4, i = t & 15;
    float p2 = 0.f, p3 = 0.f;
    const float* w3b = w3 + (o * 16 + i) * 9;
    const float* w5b = w5 + (o * 16 + i) * 25;
    #pragma unroll
    for (int ky = 0; ky < 3; ++ky)
      #pragma unroll
      for (int kx = 0; kx < 3; ++kx)
        p2 += w3b[ky * 3 + kx] * s_RS[i][(ky + 1) * 5 + (kx + 1)];
    #pragma unroll
    for (int kk = 0; kk < 25; ++kk) p3 += w5b[kk] * s_RS[i][kk];
    s_p2[o][i] = p2; s_p3[o][i] = p3;
  }
  __syncthreads();
  if (t < 16)      { float s = 0.f; for (int i = 0; i < 16; ++i) s += s_p2[t][i];      s_m2[t] = s_b3[t] + s * (1.0f/4096.0f); }
  else if (t < 32) { int o = t - 16; float s = 0.f; for (int i = 0; i < 16; ++i) s += s_p3[o][i]; s_m3[o] = s_b5[o] + s * (1.0f/4096.0f); }
  __syncthreads();

  // ---------------- softmaxes (mean(x1) == gn_b exactly) ----------------
  if (t < 3) {
    const float* m = (t == 0) ? s_gnb : (t == 1) ? s_m2 : s_m3;
    float* dst     = (t == 0) ? s_sm1 : (t == 1) ? s_sm2 : s_sm3;
    float mx = m[0];
    for (int c = 1; c < 16; ++c) mx = fmaxf(mx, m[c]);
    float e[16], ssum = 0.f;
    for (int c = 0; c < 16; ++c) { e[c] = __expf(m[c] - mx); ssum += e[c]; }
    float r = 1.0f / ssum;
    for (int c = 0; c < 16; ++c) dst[c] = e[c] * r;
  }
  __syncthreads();

  // ---------------- ECA (ca) and mixing coefficients ----------------
  if (t < 16) {
    int c = t;
    float casum = 0.f;
    #pragma unroll
    for (int v = 0; v < 3; ++v) {
      const float* m = (v == 0) ? s_gnb : (v == 1) ? s_m2 : s_m3;
      float acc = s_ecab[0] + s_ecaw[1] * m[c];
      if (c > 0)  acc += s_ecaw[0] * m[c - 1];
      if (c < 15) acc += s_ecaw[2] * m[c + 1];
      casum += sigm(acc);
    }
    s_ca[c] = casum;
    s_a1[c] = s_sm2[c] + s_sm3[c];
    s_a2[c] = s_sm1[c] + s_sm3[c];
    s_a3[c] = s_sm1[c] + s_sm2[c];
  }
  __syncthreads();

  // ---------------- effective 5x5 kernel + bias_eff ----------------
  if (t == 0) {
    float s = 0.f;
    for (int o = 0; o < 16; ++o) s += s_a2[o] * s_b3[o] + s_a3[o] * s_b5[o];
    s_scal[1] = s;
  }
  if (t < 448) {
    if (t < 400) {
      int i = t / 25, kk = t % 25, ky = kk / 5, kx = kk % 5;
      float acc = 0.f;
      #pragma unroll
      for (int o = 0; o < 16; ++o) acc += s_a3[o] * w5[((o * 16 + i) * 5 + ky) * 5 + kx];
      if (ky >= 1 && ky <= 3 && kx >= 1 && kx <= 3) {
        #pragma unroll
        for (int o = 0; o < 16; ++o) acc += s_a2[o] * w3[((o * 16 + i) * 3 + (ky - 1)) * 3 + (kx - 1)];
      }
      s_W5[i][kk] = acc;
    } else {
      int q = t - 400; s_W5[q / 3][25 + q % 3] = 0.f;
    }
  }

  // ---------------- gated GN stats: gs = sum(x*sh*sw), gq = sum((.)^2) ----------------
  {
    const int j4 = ln & 15;
    const int rr = ln >> 4;
    #pragma unroll 1
    for (int cc = 0; cc < 2; ++cc) {
      const int c = 2 * wv + cc;
      float gs = 0.f, gq = 0.f;
      const float4 swq = *(const float4*)&s_sw[c][4 * j4];
      #pragma unroll
      for (int j = 0; j < 16; ++j) {
        const int y = rr + 4 * j;
        float4 v = *(const float4*)(px + c * HWN + y * 64 + 4 * j4);
        const float shv = s_sh[c][y];
        float g0 = v.x * shv * swq.x, g1 = v.y * shv * swq.y;
        float g2 = v.z * shv * swq.z, g3 = v.w * shv * swq.w;
        gs += (g0 + g1) + (g2 + g3);
        gq += (g0 * g0 + g1 * g1) + (g2 * g2 + g3 * g3);
      }
      gs += __shfl_xor(gs, 1);  gq += __shfl_xor(gq, 1);
      gs += __shfl_xor(gs, 2);  gq += __shfl_xor(gq, 2);
      gs += __shfl_xor(gs, 4);  gq += __shfl_xor(gq, 4);
      gs += __shfl_xor(gs, 8);  gq += __shfl_xor(gq, 8);
      gs += __shfl_xor(gs, 16); gq += __shfl_xor(gq, 16);
      gs += __shfl_xor(gs, 32); gq += __shfl_xor(gq, 32);
      if (ln == 0) {
        float mu  = gs * (1.0f / 4096.0f);
        float var = gq * (1.0f / 4096.0f) - mu * mu;
        float inv = rsqrtf(var + 1e-5f);
        s_A1[c] = s_a1[c] * s_gnw[c] * inv;
        s_Cc[c] = s_a1[c] * (s_gnb[c] - mu * s_gnw[c] * inv);
      }
    }
  }
  __syncthreads();
  if (t == 0) {
    float s = s_scal[1];
    for (int c = 0; c < 16; ++c) s += s_Cc[c];
    s_scal[0] = s;
  }
  __syncthreads();

  // ---------------- write params ----------------
  float* wp = g_params + (size_t)g * PSTRIDE;
  for (int i = t; i < 1024; i += 512) wp[i]        = s_sh[i >> 6][i & 63];
  for (int i = t; i < 1024; i += 512) wp[1024 + i] = s_sw[i >> 6][i & 63];
  if (t < 448) wp[2048 + t] = s_W5[t / 28][t % 28];
  if (t < 16) { wp[2496 + t] = s_A1[t]; wp[2512 + t] = s_ca[t]; }
  if (t == 0) wp[2528] = s_scal[0];
}

// ============================ Kernel M: register-window conv + output ============================
// ROUND 11: fit the round-10 pipeline UNDER the 64-VGPR occupancy step by moving
// all wave-uniform data to SGPRs. Round 10 proved the allocator spills rather
// than step down (VGPR pinned 64, +360 MB scratch traffic). Changes:
//  - r0 via readfirstlane -> compiler-provable scalar (LLVM treats t>>6 as
//    divergent otherwise).
//  - W5[28], sh[8], A1, Ct read straight from g_params at UNIFORM addresses
//    -> s_load into SGPRs (v_fma takes 1 SGPR operand free). ~33 VGPRs freed.
//  - NO LDS at all, zero barriers. Row addresses = SGPR base + ln voffset.
// Remaining VGPR working set: vc[12]+vn[12]+ws[8]+temps ~= 45-55 < 64.
__global__ __launch_bounds__(256, 4) void ema_main(
    const float* __restrict__ x, float* __restrict__ out)
{
  const int bid  = blockIdx.x;
  const int g    = bid >> 1;          // group
  const int half = bid & 1;           // rows 0..31 / 32..63
  const int t    = threadIdx.x;
  const int ln   = t & 63;            // lane = column
  // band start row — readfirstlane makes it a provable SGPR value
  const int r0   = __builtin_amdgcn_readfirstlane((half * 4 + (t >> 6)) * 8);

  const float* px   = x   + (size_t)g * CG * HWN;
  float*       pout = out + (size_t)g * CG * HWN;
  const float* wp   = g_params + (size_t)g * PSTRIDE;

  // clamped row base offsets (all wave-uniform -> SGPRs)
  int rbase[12];
  #pragma unroll
  for (int i = 0; i < 12; ++i) {
    int a = r0 - 2 + i;
    int ac = a < 0 ? 0 : (a > 63 ? 63 : a);
    rbase[i] = ac * 64;
  }
  const bool loEdge = (r0 == 0);    // slots 0,1 invalid
  const bool hiEdge = (r0 == 56);   // slots 10,11 invalid

  float ws[8];
  #pragma unroll
  for (int j = 0; j < 8; ++j) ws[j] = 0.f;

  // prologue: channel 0 rows (branch-free loads, then value-mask edges)
  float vc[12];
  #pragma unroll
  for (int i = 0; i < 12; ++i) vc[i] = px[rbase[i] + ln];
  if (loEdge) { vc[0] = 0.f; vc[1] = 0.f; }
  if (hiEdge) { vc[10] = 0.f; vc[11] = 0.f; }

  #pragma unroll 1
  for (int c = 0; c < 16; ++c) {
    // ---- issue next channel's 12 loads first (latency hides under compute) ----
    float vn[12];
    if (c < 15) {
      const float* pn = px + (c + 1) * HWN;
      #pragma unroll
      for (int i = 0; i < 12; ++i) vn[i] = pn[rbase[i] + ln];
    }
    // ---- wave-uniform params: uniform addresses -> s_load -> SGPRs ----
    const float* wW = wp + 2048 + c * 28;     // 25 weights (uniform)
    const float A1c = wp[2496 + c];           // uniform
    const float swc = wp[1024 + c * 64 + ln]; // per-lane, coalesced, L2-hot
    float sh8[8];
    #pragma unroll
    for (int j = 0; j < 8; ++j) sh8[j] = wp[c * 64 + r0 + j];   // uniform
    // ---- compute channel c from vc (registers + shuffles only) ----
    #pragma unroll
    for (int i = 0; i < 12; ++i) {
      const float v = vc[i];
      float l1 = __shfl_up(v, 1);   l1 = (ln >= 1)  ? l1 : 0.f;
      float l2 = __shfl_up(v, 2);   l2 = (ln >= 2)  ? l2 : 0.f;
      float r1 = __shfl_down(v, 1); r1 = (ln <= 62) ? r1 : 0.f;
      float r2 = __shfl_down(v, 2); r2 = (ln <= 61) ? r2 : 0.f;
      const int jlo = (i - 4 < 0) ? 0 : i - 4;      // const after unroll
      const int jhi = (i > 7) ? 7 : i;
      #pragma unroll
      for (int j = jlo; j <= jhi; ++j) {
        const int k = i - j;                        // tap row 0..4, const
        ws[j] += wW[5 * k + 0] * l2 + wW[5 * k + 1] * l1 + wW[5 * k + 2] * v
               + wW[5 * k + 3] * r1 + wW[5 * k + 4] * r2;
      }
      if (i >= 2 && i <= 9) {                       // gated GN term (center row)
        ws[i - 2] += (A1c * sh8[i - 2]) * (swc * v);
      }
    }
    // ---- commit staged rows (vmcnt wait lands HERE, after compute) ----
    if (c < 15) {
      #pragma unroll
      for (int i = 0; i < 12; ++i) vc[i] = vn[i];
      if (loEdge) { vc[0] = 0.f; vc[1] = 0.f; }
      if (hiEdge) { vc[10] = 0.f; vc[11] = 0.f; }
    }
  }

  // epilogue: out = x * ca[c] * sigm(ws + Ct)
  const float Ct = wp[2528];
  float f[8];
  #pragma unroll
  for (int j = 0; j < 8; ++j) f[j] = sigm(ws[j] + Ct);

  #pragma unroll 1
  for (int c = 0; c < 16; ++c) {
    const float cav = wp[2512 + c];               // uniform -> SGPR
    const float* xp = px   + c * HWN + r0 * 64 + ln;
    float*       op = pout + c * HWN + r0 * 64 + ln;
    #pragma unroll
    for (int j = 0; j < 8; ++j) {
      op[j * 64] = xp[j * 64] * (cav * f[j]);
    }
  }
}

extern "C" void kernel_launch(void* const* d_in, const int* in_sizes, int n_in,
                              void* d_out, int out_size, void* d_ws, size_t ws_size,
                              hipStream_t stream) {
  const float* X  = (const float*)d_in[0];
  const float* W1 = (const float*)d_in[1];
  const float* B1 = (const float*)d_in[2];
  const float* W3 = (const float*)d_in[3];
  const float* B3 = (const float*)d_in[4];
  const float* W5 = (const float*)d_in[5];
  const float* B5 = (const float*)d_in[6];
  const float* GW = (const float*)d_in[7];
  const float* GB = (const float*)d_in[8];
  const float* EW = (const float*)d_in[9];
  const float* EB = (const float*)d_in[10];
  float* O = (float*)d_out;
  ema_prep<<<dim3(512), dim3(512), 0, stream>>>(X, W1, B1, W3, B3, W5, B5, GW, GB, EW, EB);
  ema_main<<<dim3(1024), dim3(256), 0, stream>>>(X, O);
}